// Round 3
// baseline (184.705 us; speedup 1.0000x reference)
//
#include <hip/hip_runtime.h>
#include <stdint.h>

typedef float    f32x4 __attribute__((ext_vector_type(4)));
typedef short    s16x8 __attribute__((ext_vector_type(8)));
typedef short    s16x4 __attribute__((ext_vector_type(4)));
typedef unsigned short u16;
typedef uint32_t u32;

#define DEVINL __device__ __forceinline__

DEVINL float bf2f(u16 u) { union { u32 i; float f; } x; x.i = ((u32)u) << 16; return x.f; }
DEVINL u16 f2bf(float f) {
  union { float f; u32 i; } x; x.f = f;
  u32 i = x.i;
  return (u16)((i + 0x7FFFu + ((i >> 16) & 1u)) >> 16);  // RNE
}

DEVINL void gload16(const void* g, void* l) {
  __builtin_amdgcn_global_load_lds((const __attribute__((address_space(1))) void*)g,
                                   (__attribute__((address_space(3))) void*)l,
                                   16, 0, 0);
}

// ---------------------------------------------------------------- conv x->bf16
__global__ __launch_bounds__(256) void k_conv_bf16(const float* __restrict__ x,
                                                   u16* __restrict__ xb, int n8) {
  int stride = gridDim.x * blockDim.x;
  for (int i = blockIdx.x * blockDim.x + threadIdx.x; i < n8; i += stride) {
    const f32x4* p = (const f32x4*)(x + (size_t)i * 8);
    f32x4 a = p[0], b = p[1];
    s16x8 o;
    o[0] = (short)f2bf(a[0]); o[1] = (short)f2bf(a[1]);
    o[2] = (short)f2bf(a[2]); o[3] = (short)f2bf(a[3]);
    o[4] = (short)f2bf(b[0]); o[5] = (short)f2bf(b[1]);
    o[6] = (short)f2bf(b[2]); o[7] = (short)f2bf(b[3]);
    *(s16x8*)(xb + (size_t)i * 8) = o;
  }
}

// ---------------------------------------------- W[K][N] fp32 -> Wt[N][K] bf16
__global__ __launch_bounds__(256) void k_transpose_bf16(const float* __restrict__ W,
                                                        u16* __restrict__ Wt, int K, int N) {
  __shared__ __align__(16) float t[64][65];
  int nb = N >> 6;
  int tn = blockIdx.x % nb, tk = blockIdx.x / nb;
  int n0 = tn << 6, k0 = tk << 6;
  int tid = threadIdx.x;
  int cr = tid >> 4, cc = (tid & 15) << 2;
#pragma unroll
  for (int i = 0; i < 4; i++) {
    int r = cr + (i << 4);
    f32x4 v = *(const f32x4*)(W + (size_t)(k0 + r) * N + n0 + cc);
    t[r][cc] = v[0]; t[r][cc + 1] = v[1]; t[r][cc + 2] = v[2]; t[r][cc + 3] = v[3];
  }
  __syncthreads();
#pragma unroll
  for (int i = 0; i < 4; i++) {
    int nn = cr + (i << 4);
    s16x4 o;
    o[0] = (short)f2bf(t[cc    ][nn]);
    o[1] = (short)f2bf(t[cc + 1][nn]);
    o[2] = (short)f2bf(t[cc + 2][nn]);
    o[3] = (short)f2bf(t[cc + 3][nn]);
    *(s16x4*)(Wt + (size_t)(n0 + nn) * K + k0 + cc) = o;
  }
}

// ------------------------------------------------------------------- GEMM
// C[M][N] = A[M][K=512] * Bt[N][K=512]^T, bf16 in / fp32 acc.
// 256x256 tile, 512 threads (8 waves 2Mx4N, wave tile 128x64), BK=64,
// 2-deep LDS buffering (128 KiB). ONE barrier per K-tile: stage(t+1) issued at
// tile start (loads hide under ~620cy of MFMA), boundary vmcnt(0)+s_barrier.
// Liveness: parity ~par was last read at tile t-1, certified by the t-1
// boundary barrier (each wave's ds_reads complete before its MFMA via
// compiler lgkm, hence before its barrier arrival). No sched_barriers --
// compiler schedules the tile body.
// EPI 0: qkv epilogue (phi on q/k, scatter to [bh][n][d] bf16 bufs)
// EPI 1: out = val + bias, fp32
template <int EPI>
__global__ __launch_bounds__(512, 1) void k_gemm(
    const u16* __restrict__ A, const u16* __restrict__ Bt,
    int nbn,
    u16* __restrict__ qph, u16* __restrict__ kph, u16* __restrict__ vv,
    float* __restrict__ out, const float* __restrict__ bias) {
  __shared__ __align__(16) u16 lsA[2][256 * 64];
  __shared__ __align__(16) u16 lsB[2][256 * 64];

  int nwg = gridDim.x;
  int bx = blockIdx.x;
  int o = (bx & 7) * (nwg >> 3) + (bx >> 3);   // XCD-contiguous chunks (nwg%8==0)
  int bm = o / nbn, bn = o % nbn;
  int m0 = bm << 8, n0 = bn << 8;
  int tid = threadIdx.x;
  int w = tid >> 6, lane = tid & 63;
  int lnlo = lane & 15, lnhi = lane >> 4;
  int wr = w >> 2, wc = w & 3;                  // 2 x 4 wave grid

  // staging: tile = 256 rows x 8 chunks(16B); thread owns chunks tid+i*512.
  // LDS dest linear in chunk id (wave-uniform base + lane*16 ok); global col
  // pre-swizzled: gch = chl ^ (row&7)  (involution, matches frag-read swizzle)
  const u16* gAp[4]; const u16* gBp[4]; int ldst[4];
#pragma unroll
  for (int i = 0; i < 4; i++) {
    int c = tid + i * 512;
    int row = c >> 3, chl = c & 7;
    int gch = chl ^ (row & 7);
    gAp[i] = A + (size_t)(m0 + row) * 512 + gch * 8;
    gBp[i] = Bt + (size_t)(n0 + row) * 512 + gch * 8;
    ldst[i] = c * 8;
  }

  // fragment LDS offsets (u16 units), swizzled read side
  int offA[2][8], offB[2][4];
#pragma unroll
  for (int ks = 0; ks < 2; ks++) {
#pragma unroll
    for (int f = 0; f < 8; f++) {
      int r = wr * 128 + f * 16 + lnlo;
      offA[ks][f] = (r * 8 + ((ks * 4 + lnhi) ^ (r & 7))) * 8;
    }
#pragma unroll
    for (int f = 0; f < 4; f++) {
      int r = wc * 64 + f * 16 + lnlo;
      offB[ks][f] = (r * 8 + ((ks * 4 + lnhi) ^ (r & 7))) * 8;
    }
  }

  auto stage = [&](int t) {
    int par = t & 1, k0 = t * 64;
#pragma unroll
    for (int i = 0; i < 4; i++) gload16(gAp[i] + k0, &lsA[par][ldst[i]]);
#pragma unroll
    for (int i = 0; i < 4; i++) gload16(gBp[i] + k0, &lsB[par][ldst[i]]);
  };

  f32x4 acc[8][4] = {};

  stage(0);
  asm volatile("s_waitcnt vmcnt(0)" ::: "memory");
  __builtin_amdgcn_s_barrier();

  for (int t = 0; t < 8; t++) {
    int par = t & 1;
    if (t < 7) stage(t + 1);      // into ~par: freed by previous boundary barrier
    const u16* La = &lsA[par][0];
    const u16* Lb = &lsB[par][0];
#pragma unroll
    for (int ks = 0; ks < 2; ks++) {
      s16x8 af[8], bf[4];
#pragma unroll
      for (int f = 0; f < 8; f++) af[f] = *(const s16x8*)(La + offA[ks][f]);
#pragma unroll
      for (int f = 0; f < 4; f++) bf[f] = *(const s16x8*)(Lb + offB[ks][f]);
      __builtin_amdgcn_s_setprio(1);
#pragma unroll
      for (int mf = 0; mf < 8; mf++)
#pragma unroll
        for (int nf = 0; nf < 4; nf++)
          acc[mf][nf] = __builtin_amdgcn_mfma_f32_16x16x32_bf16(af[mf], bf[nf], acc[mf][nf], 0, 0, 0);
      __builtin_amdgcn_s_setprio(0);
    }
    if (t < 7) {
      asm volatile("s_waitcnt vmcnt(0)" ::: "memory");  // tile t+1 landed (issued ~620cy ago)
      __builtin_amdgcn_s_barrier();                      // all waves done reading par
    }
  }

  int gmB = m0 + wr * 128;
  int gnB = n0 + wc * 64;
  if (EPI == 0) {
#pragma unroll
    for (int mf = 0; mf < 8; mf++) {
#pragma unroll
      for (int nf = 0; nf < 4; nf++) {
        int col = gnB + nf * 16 + lnlo;
        int sec = col >> 9;
        int hh = (col >> 6) & 7;
        int dd = col & 63;
        u16* dst = (sec == 0) ? qph : ((sec == 1) ? kph : vv);
#pragma unroll
        for (int r = 0; r < 4; r++) {
          int rowm = gmB + mf * 16 + lnhi * 4 + r;
          float val = acc[mf][nf][r];
          if (sec < 2) val = (val > 0.f) ? (val + 1.f) : __expf(val);  // elu+1
          int bidx = rowm >> 12, tok = rowm & 4095;
          dst[(((size_t)(bidx * 8 + hh) * 4096 + tok) << 6) + dd] = f2bf(val);
        }
      }
    }
  } else {
#pragma unroll
    for (int mf = 0; mf < 8; mf++) {
#pragma unroll
      for (int nf = 0; nf < 4; nf++) {
        int col = gnB + nf * 16 + lnlo;
        float bv = bias[col];
#pragma unroll
        for (int r = 0; r < 4; r++) {
          int rowm = gmB + mf * 16 + lnhi * 4 + r;
          out[(size_t)rowm * 512 + col] = acc[mf][nf][r] + bv;
        }
      }
    }
  }
}

// -------------------------------------------- KV[d][e] partials + Ksum[d]
// grid = 64 bh * 16 k-splits; 256 tokens per block; 4x4 register tile/thread.
__global__ __launch_bounds__(256) void k_kv(const u16* __restrict__ kphi,
                                            const u16* __restrict__ vbuf,
                                            float* __restrict__ kvpart,
                                            float* __restrict__ kspart) {
  __shared__ __align__(16) float kf[16][64];
  __shared__ __align__(16) float vf[16][64];
  int bx = blockIdx.x;
  int bh = bx >> 4, ck = bx & 15;
  int tid = threadIdx.x;
  size_t base = ((size_t)bh * 4096 + ck * 256) * 64;
  float acc[4][4] = {};
  float ks[4] = {0.f, 0.f, 0.f, 0.f};
  int dq = tid >> 4, eq = tid & 15;
  int d0 = dq * 4, e0 = eq * 4;
  int half = tid >> 7;            // 0: stage kphi, 1: stage v
  int t2 = tid & 127;
  int srow = t2 >> 3, sch = t2 & 7;

  for (int step = 0; step < 16; step++) {
    {
      const u16* src = (half ? vbuf : kphi) + base + (size_t)(step * 16 + srow) * 64 + sch * 8;
      s16x8 v8 = *(const s16x8*)src;
      float* dst = (half ? &vf[0][0] : &kf[0][0]) + srow * 64 + sch * 8;
      f32x4 lo = {bf2f((u16)v8[0]), bf2f((u16)v8[1]), bf2f((u16)v8[2]), bf2f((u16)v8[3])};
      f32x4 hi = {bf2f((u16)v8[4]), bf2f((u16)v8[5]), bf2f((u16)v8[6]), bf2f((u16)v8[7])};
      *(f32x4*)dst = lo;
      *(f32x4*)(dst + 4) = hi;
    }
    __syncthreads();
#pragma unroll
    for (int tk = 0; tk < 16; tk++) {
      f32x4 kq = *(const f32x4*)&kf[tk][d0];
      f32x4 vq = *(const f32x4*)&vf[tk][e0];
#pragma unroll
      for (int i = 0; i < 4; i++)
#pragma unroll
        for (int j = 0; j < 4; j++) acc[i][j] += kq[i] * vq[j];
      if (eq == 0) {
#pragma unroll
        for (int i = 0; i < 4; i++) ks[i] += kq[i];
      }
    }
    __syncthreads();
  }
  size_t pb = (size_t)(bh * 16 + ck) * 4096;
#pragma unroll
  for (int i = 0; i < 4; i++) {
    f32x4 o = {acc[i][0], acc[i][1], acc[i][2], acc[i][3]};
    *(f32x4*)(kvpart + pb + (size_t)(d0 + i) * 64 + e0) = o;
  }
  if (eq == 0) {
    f32x4 o = {ks[0], ks[1], ks[2], ks[3]};
    *(f32x4*)(kspart + (size_t)(bh * 16 + ck) * 64 + d0) = o;
  }
}

// --------------------- reduce partials -> KVt[e][d] bf16 (pre-swizzled) + Ksum
__global__ __launch_bounds__(256) void k_kvred(const float* __restrict__ kvpart,
                                               const float* __restrict__ kspart,
                                               u16* __restrict__ kvt_sw,
                                               float* __restrict__ ksum) {
  int bh = blockIdx.x;
  int tid = threadIdx.x;
  int e = tid >> 2, d0 = (tid & 3) * 16;
  size_t pb = (size_t)bh * 16 * 4096;
#pragma unroll
  for (int dd = 0; dd < 16; dd++) {
    int d = d0 + dd;
    float s = 0.f;
#pragma unroll
    for (int c = 0; c < 16; c++) s += kvpart[pb + (size_t)c * 4096 + d * 64 + e];
    int chs = (d >> 3) ^ (e & 7);                      // pre-swizzle for LDS reads
    kvt_sw[((size_t)bh * 64 + e) * 64 + chs * 8 + (d & 7)] = f2bf(s);
  }
  if (tid < 64) {
    float s = 0.f;
#pragma unroll
    for (int c = 0; c < 16; c++) s += kspart[(size_t)bh * 1024 + c * 64 + tid];
    ksum[bh * 64 + tid] = s;
  }
}

// ------------------------- y[tok][h*64+e] = (q_phi @ KV) / (q_phi . Ksum + eps)
__global__ __launch_bounds__(256, 2) void k_attnout(const u16* __restrict__ qphi,
                                                    const u16* __restrict__ kvt_sw,
                                                    const float* __restrict__ ksum,
                                                    u16* __restrict__ y) {
  __shared__ __align__(16) u16 qa[256 * 64];  // 32 KB, swizzled
  __shared__ __align__(16) u16 bb[64 * 64];   // 8 KB, swizzled (pre-swizzled global)
  __shared__ float ksl[64];
  __shared__ float rdnl[256];
  int bx = blockIdx.x;
  int bh = bx >> 4, tch = bx & 15;
  int b = bh >> 3, hh = bh & 7;
  int tid = threadIdx.x, w = tid >> 6, lane = tid & 63;
  int lnlo = lane & 15, lnhi = lane >> 4;
  size_t qbase = ((size_t)bh * 4096 + tch * 256) * 64;

#pragma unroll
  for (int i = 0; i < 8; i++) {
    int c = i * 256 + tid;
    int row = c >> 3, ch = c & 7;
    int gcol = (ch ^ (row & 7)) << 3;
    gload16(qphi + qbase + (size_t)row * 64 + gcol, &qa[c * 8]);
  }
#pragma unroll
  for (int i = 0; i < 2; i++) {
    int c = i * 256 + tid;
    gload16(kvt_sw + (size_t)bh * 4096 + c * 8, &bb[c * 8]);
  }
  if (tid < 64) ksl[tid] = ksum[bh * 64 + tid];
  __syncthreads();

  {  // denom (reciprocal) for token row = tid
    float den = 0.f;
#pragma unroll
    for (int ch = 0; ch < 8; ch++) {
      s16x8 v8 = *(const s16x8*)&qa[tid * 64 + ((ch ^ (tid & 7)) << 3)];
#pragma unroll
      for (int j = 0; j < 8; j++) den += bf2f((u16)v8[j]) * ksl[ch * 8 + j];
    }
    rdnl[tid] = 1.f / (den + 1e-6f);
  }
  __syncthreads();

  f32x4 acc[4][4] = {};
#pragma unroll
  for (int kk = 0; kk < 2; kk++) {
    s16x8 af[4], bfr[4];
#pragma unroll
    for (int f = 0; f < 4; f++) {
      int ra = w * 64 + f * 16 + lnlo;
      int ca = (kk * 4 + lnhi) ^ (ra & 7);
      af[f] = *(const s16x8*)&qa[ra * 64 + ca * 8];
      int rb = f * 16 + lnlo;
      int cb = (kk * 4 + lnhi) ^ (rb & 7);
      bfr[f] = *(const s16x8*)&bb[rb * 64 + cb * 8];
    }
#pragma unroll
    for (int mf = 0; mf < 4; mf++)
#pragma unroll
      for (int nf = 0; nf < 4; nf++)
        acc[mf][nf] = __builtin_amdgcn_mfma_f32_16x16x32_bf16(af[mf], bfr[nf], acc[mf][nf], 0, 0, 0);
  }

  size_t yrow0 = (size_t)b * 4096 + tch * 256;
#pragma unroll
  for (int mf = 0; mf < 4; mf++) {
#pragma unroll
    for (int nf = 0; nf < 4; nf++) {
      int e = nf * 16 + lnlo;
#pragma unroll
      for (int r = 0; r < 4; r++) {
        int tl = w * 64 + mf * 16 + lnhi * 4 + r;
        float val = acc[mf][nf][r] * rdnl[tl];
        y[(yrow0 + tl) * 512 + hh * 64 + e] = f2bf(val);
      }
    }
  }
}

// ------------------------------------------------------------------ launch
#define OFF_XB     ((size_t)0)             // 33,554,432  (also aliased as Y)
#define OFF_WQKVT  ((size_t)33554432)      //  1,572,864
#define OFF_WOUTT  ((size_t)35127296)      //    524,288
#define OFF_QPHI   ((size_t)35651584)      // 33,554,432
#define OFF_KPHI   ((size_t)69206016)      // 33,554,432
#define OFF_VBUF   ((size_t)102760448)     // 33,554,432
#define OFF_KVPART ((size_t)136314880)     // 16,777,216
#define OFF_KSPART ((size_t)153092096)     //    262,144
#define OFF_KVT    ((size_t)153354240)     //    524,288
#define OFF_KSUM   ((size_t)153878528)     //     16,384

extern "C" void kernel_launch(void* const* d_in, const int* in_sizes, int n_in,
                              void* d_out, int out_size, void* d_ws, size_t ws_size,
                              hipStream_t stream) {
  const float* x    = (const float*)d_in[0];
  const float* Wqkv = (const float*)d_in[1];
  const float* Wout = (const float*)d_in[2];
  const float* bout = (const float*)d_in[3];
  float* out = (float*)d_out;
  char* ws = (char*)d_ws;

  u16* xb     = (u16*)(ws + OFF_XB);
  u16* y      = (u16*)(ws + OFF_XB);  // alias: xb dead after GEMM1
  u16* wqkvt  = (u16*)(ws + OFF_WQKVT);
  u16* woutt  = (u16*)(ws + OFF_WOUTT);
  u16* qphi   = (u16*)(ws + OFF_QPHI);
  u16* kphi   = (u16*)(ws + OFF_KPHI);
  u16* vbuf   = (u16*)(ws + OFF_VBUF);
  float* kvpart = (float*)(ws + OFF_KVPART);
  float* kspart = (float*)(ws + OFF_KSPART);
  u16* kvt_sw = (u16*)(ws + OFF_KVT);
  float* ksum = (float*)(ws + OFF_KSUM);

  k_conv_bf16<<<2048, 256, 0, stream>>>(x, xb, 16777216 / 8);
  k_transpose_bf16<<<(1536 / 64) * (512 / 64), 256, 0, stream>>>(Wqkv, wqkvt, 512, 1536);
  k_transpose_bf16<<<(512 / 64) * (512 / 64), 256, 0, stream>>>(Wout, woutt, 512, 512);

  // qkv = xb @ Wqkv  (+ phi epilogue, scatter per-head)  M=32768 N=1536: 128x6=768 blocks
  k_gemm<0><<<768, 512, 0, stream>>>(xb, wqkvt, 6, qphi, kphi, vbuf, nullptr, nullptr);
  k_kv<<<64 * 16, 256, 0, stream>>>(kphi, vbuf, kvpart, kspart);
  k_kvred<<<64, 256, 0, stream>>>(kvpart, kspart, kvt_sw, ksum);
  k_attnout<<<64 * 16, 256, 0, stream>>>(qphi, kvt_sw, ksum, y);
  // out = y @ Wout + b  M=32768 N=512: 128x2=256 blocks
  k_gemm<1><<<256, 512, 0, stream>>>(y, woutt, 2, nullptr, nullptr, nullptr, out, bout);
}

// Round 4
// 178.499 us; speedup vs baseline: 1.0348x; 1.0348x over previous
//
#include <hip/hip_runtime.h>
#include <stdint.h>

typedef float    f32x4 __attribute__((ext_vector_type(4)));
typedef short    s16x8 __attribute__((ext_vector_type(8)));
typedef short    s16x4 __attribute__((ext_vector_type(4)));
typedef unsigned short u16;
typedef uint32_t u32;

#define DEVINL __device__ __forceinline__

DEVINL float bf2f(u16 u) { union { u32 i; float f; } x; x.i = ((u32)u) << 16; return x.f; }
DEVINL u16 f2bf(float f) {
  union { float f; u32 i; } x; x.f = f;
  u32 i = x.i;
  return (u16)((i + 0x7FFFu + ((i >> 16) & 1u)) >> 16);  // RNE
}

DEVINL void gload16(const void* g, void* l) {
  __builtin_amdgcn_global_load_lds((const __attribute__((address_space(1))) void*)g,
                                   (__attribute__((address_space(3))) void*)l,
                                   16, 0, 0);
}

// ---------------------------------------------------------------- conv x->bf16
__global__ __launch_bounds__(256) void k_conv_bf16(const float* __restrict__ x,
                                                   u16* __restrict__ xb, int n8) {
  int stride = gridDim.x * blockDim.x;
  for (int i = blockIdx.x * blockDim.x + threadIdx.x; i < n8; i += stride) {
    const f32x4* p = (const f32x4*)(x + (size_t)i * 8);
    f32x4 a = p[0], b = p[1];
    s16x8 o;
    o[0] = (short)f2bf(a[0]); o[1] = (short)f2bf(a[1]);
    o[2] = (short)f2bf(a[2]); o[3] = (short)f2bf(a[3]);
    o[4] = (short)f2bf(b[0]); o[5] = (short)f2bf(b[1]);
    o[6] = (short)f2bf(b[2]); o[7] = (short)f2bf(b[3]);
    *(s16x8*)(xb + (size_t)i * 8) = o;
  }
}

// ---------------------------------------------- W[K][N] fp32 -> Wt[N][K] bf16
__global__ __launch_bounds__(256) void k_transpose_bf16(const float* __restrict__ W,
                                                        u16* __restrict__ Wt, int K, int N) {
  __shared__ __align__(16) float t[64][65];
  int nb = N >> 6;
  int tn = blockIdx.x % nb, tk = blockIdx.x / nb;
  int n0 = tn << 6, k0 = tk << 6;
  int tid = threadIdx.x;
  int cr = tid >> 4, cc = (tid & 15) << 2;
#pragma unroll
  for (int i = 0; i < 4; i++) {
    int r = cr + (i << 4);
    f32x4 v = *(const f32x4*)(W + (size_t)(k0 + r) * N + n0 + cc);
    t[r][cc] = v[0]; t[r][cc + 1] = v[1]; t[r][cc + 2] = v[2]; t[r][cc + 3] = v[3];
  }
  __syncthreads();
#pragma unroll
  for (int i = 0; i < 4; i++) {
    int nn = cr + (i << 4);
    s16x4 o;
    o[0] = (short)f2bf(t[cc    ][nn]);
    o[1] = (short)f2bf(t[cc + 1][nn]);
    o[2] = (short)f2bf(t[cc + 2][nn]);
    o[3] = (short)f2bf(t[cc + 3][nn]);
    *(s16x4*)(Wt + (size_t)(n0 + nn) * K + k0 + cc) = o;
  }
}

// ------------------------------------------------------------------- GEMM
// C[M][N] = A[M][K=512] * Bt[N][K=512]^T, bf16 in / fp32 acc.
// 256x256 tile, 512 threads (8 waves 2Mx4N, wave tile 128x64).
// m201-granularity schedule: BK=32, 16 K-tiles, 3-deep LDS buffers (96 KiB),
// staging runs 2 tiles ahead -> main-loop wait is counted vmcnt(4), never 0
// until the tail. Per K-tile 2 phases:
//   a: {B(4)+A_mf0-3(4) ds_read_b128, 2 stage-issues(t+2 A), barrier,
//       setprio+16 MFMA, barrier}
//   b: {A_mf4-7(4) reads, 2 stage-issues(t+2 B), barrier, 16 MFMA,
//       vmcnt(4), barrier}
// Race ledger: stage(t+2) targets buf (t+2)%3, last read in tile t-1; every
// wave's t-1 reads complete before its MFMA (compiler lgkm) hence before the
// t-1-end barrier; stages issue after it. vmcnt: at end of tile t outstanding
// = {t+1,t+2} stages = 8 -> vmcnt(4) certifies t+1 landed. No sched_barriers.
// EPI 0: qkv epilogue (phi on q/k, scatter to [bh][n][d] bf16 bufs)
// EPI 1: out = val + bias, fp32
template <int EPI>
__global__ __launch_bounds__(512, 1) void k_gemm(
    const u16* __restrict__ A, const u16* __restrict__ Bt,
    int nbn,
    u16* __restrict__ qph, u16* __restrict__ kph, u16* __restrict__ vv,
    float* __restrict__ out, const float* __restrict__ bias) {
  __shared__ __align__(16) u16 lsA[3][256 * 32];
  __shared__ __align__(16) u16 lsB[3][256 * 32];

  int nwg = gridDim.x;
  int bx = blockIdx.x;
  int o = (bx & 7) * (nwg >> 3) + (bx >> 3);   // XCD-contiguous chunks (nwg%8==0)
  int bm = o / nbn, bn = o % nbn;
  int m0 = bm << 8, n0 = bn << 8;
  int tid = threadIdx.x;
  int w = tid >> 6, lane = tid & 63;
  int lnlo = lane & 15, lnhi = lane >> 4;
  int wr = w >> 2, wc = w & 3;                  // 2 x 4 wave grid

  // staging: per BK=32 tile, A = 256 rows x 4 chunks(16B) = 1024 chunks;
  // thread owns chunks tid and tid+512 (2 gload16 for A, 2 for B).
  // LDS dest linear in chunk id; global col pre-swizzled with the same
  // involution used on the read side: ch' = ch ^ ((row>>1)&3)  (2-way free)
  const u16* gAp[2]; const u16* gBp[2]; int ldst[2];
#pragma unroll
  for (int i = 0; i < 2; i++) {
    int c = tid + i * 512;
    int row = c >> 2, ch = c & 3;
    int gch = ch ^ ((row >> 1) & 3);
    gAp[i] = A + (size_t)(m0 + row) * 512 + gch * 8;
    gBp[i] = Bt + (size_t)(n0 + row) * 512 + gch * 8;
    ldst[i] = c * 8;
  }

  // fragment LDS offsets (u16 units), swizzled read side, row stride 32
  int offA[8], offB[4];
#pragma unroll
  for (int f = 0; f < 8; f++) {
    int r = wr * 128 + f * 16 + lnlo;
    offA[f] = r * 32 + (lnhi ^ ((r >> 1) & 3)) * 8;
  }
#pragma unroll
  for (int f = 0; f < 4; f++) {
    int r = wc * 64 + f * 16 + lnlo;
    offB[f] = r * 32 + (lnhi ^ ((r >> 1) & 3)) * 8;
  }

  f32x4 acc[8][4] = {};

  // prologue: stage tiles 0 and 1 fully
#pragma unroll
  for (int i = 0; i < 2; i++) gload16(gAp[i], &lsA[0][ldst[i]]);
#pragma unroll
  for (int i = 0; i < 2; i++) gload16(gBp[i], &lsB[0][ldst[i]]);
#pragma unroll
  for (int i = 0; i < 2; i++) gload16(gAp[i] + 32, &lsA[1][ldst[i]]);
#pragma unroll
  for (int i = 0; i < 2; i++) gload16(gBp[i] + 32, &lsB[1][ldst[i]]);
  asm volatile("s_waitcnt vmcnt(4)" ::: "memory");   // tile 0 landed; tile 1 flying
  __builtin_amdgcn_s_barrier();

#pragma unroll
  for (int t = 0; t < 16; t++) {
    int buf = t % 3;
    const u16* La = &lsA[buf][0];
    const u16* Lb = &lsB[buf][0];
    int k2 = (t + 2) * 32;
    int b2 = (t + 2) % 3;

    // ---- phase a: B all + A mf0-3; stage A of t+2
    s16x8 bf[4], af[4];
#pragma unroll
    for (int f = 0; f < 4; f++) bf[f] = *(const s16x8*)(Lb + offB[f]);
#pragma unroll
    for (int f = 0; f < 4; f++) af[f] = *(const s16x8*)(La + offA[f]);
    if (t < 14) {
#pragma unroll
      for (int i = 0; i < 2; i++) gload16(gAp[i] + k2, &lsA[b2][ldst[i]]);
    }
    __builtin_amdgcn_s_barrier();
    __builtin_amdgcn_s_setprio(1);
#pragma unroll
    for (int mf = 0; mf < 4; mf++)
#pragma unroll
      for (int nf = 0; nf < 4; nf++)
        acc[mf][nf] = __builtin_amdgcn_mfma_f32_16x16x32_bf16(af[mf], bf[nf], acc[mf][nf], 0, 0, 0);
    __builtin_amdgcn_s_setprio(0);
    __builtin_amdgcn_s_barrier();

    // ---- phase b: A mf4-7; stage B of t+2
    s16x8 af2[4];
#pragma unroll
    for (int f = 0; f < 4; f++) af2[f] = *(const s16x8*)(La + offA[4 + f]);
    if (t < 14) {
#pragma unroll
      for (int i = 0; i < 2; i++) gload16(gBp[i] + k2, &lsB[b2][ldst[i]]);
    }
    __builtin_amdgcn_s_barrier();
    __builtin_amdgcn_s_setprio(1);
#pragma unroll
    for (int mf = 0; mf < 4; mf++)
#pragma unroll
      for (int nf = 0; nf < 4; nf++)
        acc[4 + mf][nf] = __builtin_amdgcn_mfma_f32_16x16x32_bf16(af2[mf], bf[nf], acc[4 + mf][nf], 0, 0, 0);
    __builtin_amdgcn_s_setprio(0);
    if (t <= 13)      asm volatile("s_waitcnt vmcnt(4)" ::: "memory");  // t+1 landed
    else if (t == 14) asm volatile("s_waitcnt vmcnt(0)" ::: "memory");  // tail
    if (t < 15) __builtin_amdgcn_s_barrier();
  }

  int gmB = m0 + wr * 128;
  int gnB = n0 + wc * 64;
  if (EPI == 0) {
#pragma unroll
    for (int mf = 0; mf < 8; mf++) {
#pragma unroll
      for (int nf = 0; nf < 4; nf++) {
        int col = gnB + nf * 16 + lnlo;
        int sec = col >> 9;
        int hh = (col >> 6) & 7;
        int dd = col & 63;
        u16* dst = (sec == 0) ? qph : ((sec == 1) ? kph : vv);
#pragma unroll
        for (int r = 0; r < 4; r++) {
          int rowm = gmB + mf * 16 + lnhi * 4 + r;
          float val = acc[mf][nf][r];
          if (sec < 2) val = (val > 0.f) ? (val + 1.f) : __expf(val);  // elu+1
          int bidx = rowm >> 12, tok = rowm & 4095;
          dst[(((size_t)(bidx * 8 + hh) * 4096 + tok) << 6) + dd] = f2bf(val);
        }
      }
    }
  } else {
#pragma unroll
    for (int mf = 0; mf < 8; mf++) {
#pragma unroll
      for (int nf = 0; nf < 4; nf++) {
        int col = gnB + nf * 16 + lnlo;
        float bv = bias[col];
#pragma unroll
        for (int r = 0; r < 4; r++) {
          int rowm = gmB + mf * 16 + lnhi * 4 + r;
          out[(size_t)rowm * 512 + col] = acc[mf][nf][r] + bv;
        }
      }
    }
  }
}

// -------------------------------------------- KV[d][e] partials + Ksum[d]
// grid = 64 bh * 16 k-splits; 256 tokens per block; 4x4 register tile/thread.
__global__ __launch_bounds__(256) void k_kv(const u16* __restrict__ kphi,
                                            const u16* __restrict__ vbuf,
                                            float* __restrict__ kvpart,
                                            float* __restrict__ kspart) {
  __shared__ __align__(16) float kf[16][64];
  __shared__ __align__(16) float vf[16][64];
  int bx = blockIdx.x;
  int bh = bx >> 4, ck = bx & 15;
  int tid = threadIdx.x;
  size_t base = ((size_t)bh * 4096 + ck * 256) * 64;
  float acc[4][4] = {};
  float ks[4] = {0.f, 0.f, 0.f, 0.f};
  int dq = tid >> 4, eq = tid & 15;
  int d0 = dq * 4, e0 = eq * 4;
  int half = tid >> 7;            // 0: stage kphi, 1: stage v
  int t2 = tid & 127;
  int srow = t2 >> 3, sch = t2 & 7;

  for (int step = 0; step < 16; step++) {
    {
      const u16* src = (half ? vbuf : kphi) + base + (size_t)(step * 16 + srow) * 64 + sch * 8;
      s16x8 v8 = *(const s16x8*)src;
      float* dst = (half ? &vf[0][0] : &kf[0][0]) + srow * 64 + sch * 8;
      f32x4 lo = {bf2f((u16)v8[0]), bf2f((u16)v8[1]), bf2f((u16)v8[2]), bf2f((u16)v8[3])};
      f32x4 hi = {bf2f((u16)v8[4]), bf2f((u16)v8[5]), bf2f((u16)v8[6]), bf2f((u16)v8[7])};
      *(f32x4*)dst = lo;
      *(f32x4*)(dst + 4) = hi;
    }
    __syncthreads();
#pragma unroll
    for (int tk = 0; tk < 16; tk++) {
      f32x4 kq = *(const f32x4*)&kf[tk][d0];
      f32x4 vq = *(const f32x4*)&vf[tk][e0];
#pragma unroll
      for (int i = 0; i < 4; i++)
#pragma unroll
        for (int j = 0; j < 4; j++) acc[i][j] += kq[i] * vq[j];
      if (eq == 0) {
#pragma unroll
        for (int i = 0; i < 4; i++) ks[i] += kq[i];
      }
    }
    __syncthreads();
  }
  size_t pb = (size_t)(bh * 16 + ck) * 4096;
#pragma unroll
  for (int i = 0; i < 4; i++) {
    f32x4 o = {acc[i][0], acc[i][1], acc[i][2], acc[i][3]};
    *(f32x4*)(kvpart + pb + (size_t)(d0 + i) * 64 + e0) = o;
  }
  if (eq == 0) {
    f32x4 o = {ks[0], ks[1], ks[2], ks[3]};
    *(f32x4*)(kspart + (size_t)(bh * 16 + ck) * 64 + d0) = o;
  }
}

// --------------------- reduce partials -> KVt[e][d] bf16 (pre-swizzled) + Ksum
__global__ __launch_bounds__(256) void k_kvred(const float* __restrict__ kvpart,
                                               const float* __restrict__ kspart,
                                               u16* __restrict__ kvt_sw,
                                               float* __restrict__ ksum) {
  int bh = blockIdx.x;
  int tid = threadIdx.x;
  int e = tid >> 2, d0 = (tid & 3) * 16;
  size_t pb = (size_t)bh * 16 * 4096;
#pragma unroll
  for (int dd = 0; dd < 16; dd++) {
    int d = d0 + dd;
    float s = 0.f;
#pragma unroll
    for (int c = 0; c < 16; c++) s += kvpart[pb + (size_t)c * 4096 + d * 64 + e];
    int chs = (d >> 3) ^ (e & 7);                      // pre-swizzle for LDS reads
    kvt_sw[((size_t)bh * 64 + e) * 64 + chs * 8 + (d & 7)] = f2bf(s);
  }
  if (tid < 64) {
    float s = 0.f;
#pragma unroll
    for (int c = 0; c < 16; c++) s += kspart[(size_t)bh * 1024 + c * 64 + tid];
    ksum[bh * 64 + tid] = s;
  }
}

// ------------------------- y[tok][h*64+e] = (q_phi @ KV) / (q_phi . Ksum + eps)
__global__ __launch_bounds__(256, 2) void k_attnout(const u16* __restrict__ qphi,
                                                    const u16* __restrict__ kvt_sw,
                                                    const float* __restrict__ ksum,
                                                    u16* __restrict__ y) {
  __shared__ __align__(16) u16 qa[256 * 64];  // 32 KB, swizzled
  __shared__ __align__(16) u16 bb[64 * 64];   // 8 KB, swizzled (pre-swizzled global)
  __shared__ float ksl[64];
  __shared__ float rdnl[256];
  int bx = blockIdx.x;
  int bh = bx >> 4, tch = bx & 15;
  int b = bh >> 3, hh = bh & 7;
  int tid = threadIdx.x, w = tid >> 6, lane = tid & 63;
  int lnlo = lane & 15, lnhi = lane >> 4;
  size_t qbase = ((size_t)bh * 4096 + tch * 256) * 64;

#pragma unroll
  for (int i = 0; i < 8; i++) {
    int c = i * 256 + tid;
    int row = c >> 3, ch = c & 7;
    int gcol = (ch ^ (row & 7)) << 3;
    gload16(qphi + qbase + (size_t)row * 64 + gcol, &qa[c * 8]);
  }
#pragma unroll
  for (int i = 0; i < 2; i++) {
    int c = i * 256 + tid;
    gload16(kvt_sw + (size_t)bh * 4096 + c * 8, &bb[c * 8]);
  }
  if (tid < 64) ksl[tid] = ksum[bh * 64 + tid];
  __syncthreads();

  {  // denom (reciprocal) for token row = tid
    float den = 0.f;
#pragma unroll
    for (int ch = 0; ch < 8; ch++) {
      s16x8 v8 = *(const s16x8*)&qa[tid * 64 + ((ch ^ (tid & 7)) << 3)];
#pragma unroll
      for (int j = 0; j < 8; j++) den += bf2f((u16)v8[j]) * ksl[ch * 8 + j];
    }
    rdnl[tid] = 1.f / (den + 1e-6f);
  }
  __syncthreads();

  f32x4 acc[4][4] = {};
#pragma unroll
  for (int kk = 0; kk < 2; kk++) {
    s16x8 af[4], bfr[4];
#pragma unroll
    for (int f = 0; f < 4; f++) {
      int ra = w * 64 + f * 16 + lnlo;
      int ca = (kk * 4 + lnhi) ^ (ra & 7);
      af[f] = *(const s16x8*)&qa[ra * 64 + ca * 8];
      int rb = f * 16 + lnlo;
      int cb = (kk * 4 + lnhi) ^ (rb & 7);
      bfr[f] = *(const s16x8*)&bb[rb * 64 + cb * 8];
    }
#pragma unroll
    for (int mf = 0; mf < 4; mf++)
#pragma unroll
      for (int nf = 0; nf < 4; nf++)
        acc[mf][nf] = __builtin_amdgcn_mfma_f32_16x16x32_bf16(af[mf], bfr[nf], acc[mf][nf], 0, 0, 0);
  }

  size_t yrow0 = (size_t)b * 4096 + tch * 256;
#pragma unroll
  for (int mf = 0; mf < 4; mf++) {
#pragma unroll
    for (int nf = 0; nf < 4; nf++) {
      int e = nf * 16 + lnlo;
#pragma unroll
      for (int r = 0; r < 4; r++) {
        int tl = w * 64 + mf * 16 + lnhi * 4 + r;
        float val = acc[mf][nf][r] * rdnl[tl];
        y[(yrow0 + tl) * 512 + hh * 64 + e] = f2bf(val);
      }
    }
  }
}

// ------------------------------------------------------------------ launch
#define OFF_XB     ((size_t)0)             // 33,554,432  (also aliased as Y)
#define OFF_WQKVT  ((size_t)33554432)      //  1,572,864
#define OFF_WOUTT  ((size_t)35127296)      //    524,288
#define OFF_QPHI   ((size_t)35651584)      // 33,554,432
#define OFF_KPHI   ((size_t)69206016)      // 33,554,432
#define OFF_VBUF   ((size_t)102760448)     // 33,554,432
#define OFF_KVPART ((size_t)136314880)     // 16,777,216
#define OFF_KSPART ((size_t)153092096)     //    262,144
#define OFF_KVT    ((size_t)153354240)     //    524,288
#define OFF_KSUM   ((size_t)153878528)     //     16,384

extern "C" void kernel_launch(void* const* d_in, const int* in_sizes, int n_in,
                              void* d_out, int out_size, void* d_ws, size_t ws_size,
                              hipStream_t stream) {
  const float* x    = (const float*)d_in[0];
  const float* Wqkv = (const float*)d_in[1];
  const float* Wout = (const float*)d_in[2];
  const float* bout = (const float*)d_in[3];
  float* out = (float*)d_out;
  char* ws = (char*)d_ws;

  u16* xb     = (u16*)(ws + OFF_XB);
  u16* y      = (u16*)(ws + OFF_XB);  // alias: xb dead after GEMM1
  u16* wqkvt  = (u16*)(ws + OFF_WQKVT);
  u16* woutt  = (u16*)(ws + OFF_WOUTT);
  u16* qphi   = (u16*)(ws + OFF_QPHI);
  u16* kphi   = (u16*)(ws + OFF_KPHI);
  u16* vbuf   = (u16*)(ws + OFF_VBUF);
  float* kvpart = (float*)(ws + OFF_KVPART);
  float* kspart = (float*)(ws + OFF_KSPART);
  u16* kvt_sw = (u16*)(ws + OFF_KVT);
  float* ksum = (float*)(ws + OFF_KSUM);

  k_conv_bf16<<<2048, 256, 0, stream>>>(x, xb, 16777216 / 8);
  k_transpose_bf16<<<(1536 / 64) * (512 / 64), 256, 0, stream>>>(Wqkv, wqkvt, 512, 1536);
  k_transpose_bf16<<<(512 / 64) * (512 / 64), 256, 0, stream>>>(Wout, woutt, 512, 512);

  // qkv = xb @ Wqkv  (+ phi epilogue, scatter per-head)  M=32768 N=1536: 128x6=768 blocks
  k_gemm<0><<<768, 512, 0, stream>>>(xb, wqkvt, 6, qphi, kphi, vbuf, nullptr, nullptr);
  k_kv<<<64 * 16, 256, 0, stream>>>(kphi, vbuf, kvpart, kspart);
  k_kvred<<<64, 256, 0, stream>>>(kvpart, kspart, kvt_sw, ksum);
  k_attnout<<<64 * 16, 256, 0, stream>>>(qphi, kvt_sw, ksum, y);
  // out = y @ Wout + b  M=32768 N=512: 128x2=256 blocks
  k_gemm<1><<<256, 512, 0, stream>>>(y, woutt, 2, nullptr, nullptr, nullptr, out, bout);
}